// Round 8
// baseline (374.251 us; speedup 1.0000x reference)
//
#include <hip/hip_runtime.h>
#include <hip/hip_bf16.h>

#define D_IN 128
#define F 64          // H1 == H2 == D_OUT == 64
#define R_EDGES 4096  // edges per partition block

// ===================== radix-16 partition, pass 1 (dst high 4 bits of sub-bucket) ==========
__global__ __launch_bounds__(256) void part1_kernel(
        const int* __restrict__ src, const int* __restrict__ dst, int E,
        unsigned long long M37, int cap1, uint2* __restrict__ ebufB,
        int* __restrict__ bcur1) {
    __shared__ int wcnt[64], incl64[64], cur[64], gbase[16];
    const int t = threadIdx.x, w = t >> 6, lane = t & 63;
    const int base = blockIdx.x * R_EDGES;
    const int lim = min(base + R_EDGES, E);

    if (t < 64) wcnt[t] = 0;
    __syncthreads();

    for (int i = base + t; i < lim; i += 256) {
        int d = dst[i];
        int b = (int)(((unsigned long long)(unsigned)d * M37) >> 37) >> 4;
        atomicAdd(&wcnt[b * 4 + w], 1);
    }
    __syncthreads();

    if (t < 64) {                       // exclusive scan, bin-major index b*4+w
        int v = wcnt[t], x = v;
        for (int dlt = 1; dlt < 64; dlt <<= 1) { int y = __shfl_up(x, dlt); if (lane >= dlt) x += y; }
        incl64[t] = x;
        wcnt[t] = x - v;
    }
    __syncthreads();
    if (t < 16) {
        int T = incl64[t * 4 + 3] - (t ? incl64[t * 4 - 1] : 0);
        gbase[t] = T > 0 ? atomicAdd(&bcur1[t], T) : 0;
    }
    __syncthreads();
    if (t < 64) cur[t] = gbase[t >> 2] + wcnt[t] - wcnt[(t >> 2) << 2];
    __syncthreads();

    for (int i = base + t; i < lim; i += 256) {
        int s = src[i], d = dst[i];
        int b = (int)(((unsigned long long)(unsigned)d * M37) >> 37) >> 4;
        int p = atomicAdd(&cur[b * 4 + w], 1);
        ebufB[(size_t)b * cap1 + p] = make_uint2((unsigned)s, (unsigned)d);
    }
}

// ===================== radix-16 partition, pass 2 (low 4 bits) ==========
#define BPB2 27   // blocks per L1 bucket
__global__ __launch_bounds__(256) void part2_kernel(
        const uint2* __restrict__ ebufB, const int* __restrict__ bcur1,
        unsigned long long M37, int cap1, int cap2,
        uint2* __restrict__ ebufA, int* __restrict__ bcur2) {
    __shared__ int wcnt[64], incl64[64], cur[64], gbase[16];
    const int t = threadIdx.x, w = t >> 6, lane = t & 63;
    const int b1 = blockIdx.x / BPB2, r = blockIdx.x % BPB2;
    const int cnt1 = bcur1[b1];
    const int beg = r * R_EDGES, lim = min(beg + R_EDGES, cnt1);
    if (beg >= cnt1) return;
    const uint2* in = ebufB + (size_t)b1 * cap1;

    if (t < 64) wcnt[t] = 0;
    __syncthreads();

    for (int i = beg + t; i < lim; i += 256) {
        unsigned d = in[i].y;
        int b = (int)(((unsigned long long)d * M37) >> 37) & 15;
        atomicAdd(&wcnt[b * 4 + w], 1);
    }
    __syncthreads();

    if (t < 64) {
        int v = wcnt[t], x = v;
        for (int dlt = 1; dlt < 64; dlt <<= 1) { int y = __shfl_up(x, dlt); if (lane >= dlt) x += y; }
        incl64[t] = x;
        wcnt[t] = x - v;
    }
    __syncthreads();
    if (t < 16) {
        int T = incl64[t * 4 + 3] - (t ? incl64[t * 4 - 1] : 0);
        gbase[t] = T > 0 ? atomicAdd(&bcur2[b1 * 16 + t], T) : 0;
    }
    __syncthreads();
    if (t < 64) cur[t] = gbase[t >> 2] + wcnt[t] - wcnt[(t >> 2) << 2];
    __syncthreads();

    for (int i = beg + t; i < lim; i += 256) {
        uint2 e = in[i];
        int b = (int)(((unsigned long long)e.y * M37) >> 37) & 15;
        int p = atomicAdd(&cur[b * 4 + w], 1);
        ebufA[(size_t)(b1 * 16 + b) * cap2 + p] = e;
    }
}

// ===================== sub-bucket csr base scan + offsets[n] ==========
__global__ __launch_bounds__(256) void scan256_kernel(const int* __restrict__ bcur2,
                                                      int* __restrict__ bbase,
                                                      int* __restrict__ offsets, int n, int E) {
    __shared__ int tmp[256];
    int t = threadIdx.x;
    int v = bcur2[t];
    tmp[t] = v;
    __syncthreads();
    for (int off = 1; off < 256; off <<= 1) {
        int a = (t >= off) ? tmp[t - off] : 0;
        __syncthreads();
        if (t >= off) tmp[t] += a;
        __syncthreads();
    }
    bbase[t] = tmp[t] - v;
    if (t == 0) offsets[n] = E;
}

// ===================== per-sub-bucket sort: counts, scan, csr, offsets, dinv ==========
__global__ __launch_bounds__(256) void bsort_kernel(
        const uint2* __restrict__ ebufA, const int* __restrict__ bcur2,
        const int* __restrict__ bbase, int cap2, int NPB, int n,
        int* __restrict__ csr, int* __restrict__ offsets, float* __restrict__ dinv) {
    __shared__ int cnt[512], excl[512];
    const int sb = blockIdx.x, t = threadIdx.x;
    const int node0 = sb * NPB;
    const int nn = min(NPB, n - node0);
    if (nn <= 0) return;
    const int cE = bcur2[sb];
    const int base = bbase[sb];
    const uint2* eb = ebufA + (size_t)sb * cap2;

    for (int i = t; i < 512; i += 256) cnt[i] = 0;
    __syncthreads();
    for (int i = t; i < cE; i += 256) atomicAdd(&cnt[eb[i].y - node0], 1);
    __syncthreads();

    if (t < 64) {                         // scan 512 = 8 chunks of 64, wave 0
        int carry = 0;
        for (int c = 0; c < 8; ++c) {
            int v = cnt[c * 64 + t], x = v;
            for (int dlt = 1; dlt < 64; dlt <<= 1) { int y = __shfl_up(x, dlt); if (t >= dlt) x += y; }
            excl[c * 64 + t] = carry + x - v;
            carry += __shfl(x, 63);
        }
    }
    __syncthreads();

    for (int i = t; i < nn; i += 256) {
        offsets[node0 + i] = base + excl[i];
        dinv[node0 + i] = rsqrtf((float)cnt[i] + 1.0f);
    }
    __syncthreads();
    for (int i = t; i < 512; i += 256) cnt[i] = excl[i];   // cursors
    __syncthreads();
    for (int i = t; i < cE; i += 256) {
        uint2 e = eb[i];
        int p = atomicAdd(&cnt[e.y - node0], 1);
        csr[base + p] = (int)e.x;
    }
}

// ============ GEMM (layer 1 only): h2 = dinv * (x @ W1), K=128 ============
// k4 loop unroll CAPPED at 2: full unroll spilled to scratch (R2: 1.7GB traffic).
template<int K, bool RELU_IN>
__global__ __launch_bounds__(256) void gemm_kernel(
        const float* __restrict__ A, const float* __restrict__ W,
        const float* __restrict__ dinv, float* __restrict__ h2, int n) {
    constexpr int F4 = K / 4;
    __shared__ float4 Al[64 * F4];            // swizzled: phys k4 = k4 ^ ((r>>2) & 7)
    __shared__ float  Wl[K * F];
    const int t = threadIdx.x;

    for (int i = t; i < K * F / 4; i += 256)
        ((float4*)Wl)[i] = ((const float4*)W)[i];

    const int row0 = blockIdx.x * 64;
    for (int i = t; i < 64 * F4; i += 256) {
        int r = i / F4, k4 = i % F4;
        int gr = row0 + r; if (gr >= n) gr = n - 1;
        float4 v = ((const float4*)(A + (size_t)gr * K))[k4];
        if (RELU_IN) {
            v.x = fmaxf(v.x, 0.f); v.y = fmaxf(v.y, 0.f);
            v.z = fmaxf(v.z, 0.f); v.w = fmaxf(v.w, 0.f);
        }
        Al[r * F4 + (k4 ^ ((r >> 2) & 7))] = v;
    }
    __syncthreads();

    const int rg = t >> 4, cg = t & 15;
    const int r0 = rg * 4, c0 = cg * 4;
    const int sw = rg & 7;

    float acc[4][4] = {};
#pragma unroll 2
    for (int k4 = 0; k4 < F4; ++k4) {
        float4 a[4];
#pragma unroll
        for (int i = 0; i < 4; ++i) a[i] = Al[(r0 + i) * F4 + (k4 ^ sw)];
#pragma unroll
        for (int j = 0; j < 4; ++j) {
            float4 w = *(const float4*)&Wl[(k4 * 4 + j) * F + c0];
#pragma unroll
            for (int i = 0; i < 4; ++i) {
                float av = (j == 0) ? a[i].x : (j == 1) ? a[i].y : (j == 2) ? a[i].z : a[i].w;
                acc[i][0] = fmaf(av, w.x, acc[i][0]);
                acc[i][1] = fmaf(av, w.y, acc[i][1]);
                acc[i][2] = fmaf(av, w.z, acc[i][2]);
                acc[i][3] = fmaf(av, w.w, acc[i][3]);
            }
        }
    }

#pragma unroll
    for (int i = 0; i < 4; ++i) {
        int gr = row0 + r0 + i;
        if (gr < n) {
            float dv = dinv[gr];
            float4 o = make_float4(acc[i][0] * dv, acc[i][1] * dv,
                                   acc[i][2] * dv, acc[i][3] * dv);
            *(float4*)&h2[(size_t)gr * F + c0] = o;
        }
    }
}

// ============ FUSED agg + next-layer GEMM ============
// Per 64-node block: agg phase (wave wv aggregates nodes wv*16..wv*16+15 with
// 4 gathers in flight; t = relu(b + dinv*(self + sum)) -> swizzled LDS A-tile),
// then one __syncthreads, then the register-tiled K=64 GEMM phase:
// hout = dinv * (t @ W). Eliminates the outA round-trip and gemm dispatch;
// gemm VALU work overlaps other blocks' gather stalls.
__global__ __launch_bounds__(256) void aggmm_kernel(
        const int* __restrict__ offsets, const int* __restrict__ csr,
        const float* __restrict__ dinv, const float* __restrict__ hin,
        const float* __restrict__ bvec, const float* __restrict__ W,
        float* __restrict__ hout, int n) {
    __shared__ float4 Al[64 * 16];     // 16 KB, swizzled like gemm_kernel
    __shared__ float  Wl[64 * F];      // 16 KB
    const int t = threadIdx.x;

    for (int i = t; i < 64 * F / 4; i += 256)
        ((float4*)Wl)[i] = ((const float4*)W)[i];
    // (Wl consumed only after the syncthreads below)

    const int row0 = blockIdx.x * 64;
    const int wv = t >> 6, lane = t & 63;
    const int g = lane >> 4, q = lane & 15;

    // ---- agg phase ----
    for (int i = 0; i < 16; ++i) {
        const int r = wv * 16 + i;
        const int node = row0 + r;
        if (node < n) {
            float4 acc = make_float4(0.f, 0.f, 0.f, 0.f);
            if (g == 0) acc = *(const float4*)&hin[(size_t)node * F + q * 4];  // self
            const int beg = offsets[node], end = offsets[node + 1];
            int j = beg + g;
            for (; j + 12 < end; j += 16) {           // 4 gathers in flight per lane
                int s0 = csr[j], s1 = csr[j + 4], s2 = csr[j + 8], s3 = csr[j + 12];
                float4 v0 = *(const float4*)&hin[(size_t)s0 * F + q * 4];
                float4 v1 = *(const float4*)&hin[(size_t)s1 * F + q * 4];
                float4 v2 = *(const float4*)&hin[(size_t)s2 * F + q * 4];
                float4 v3 = *(const float4*)&hin[(size_t)s3 * F + q * 4];
                acc.x += (v0.x + v1.x) + (v2.x + v3.x);
                acc.y += (v0.y + v1.y) + (v2.y + v3.y);
                acc.z += (v0.z + v1.z) + (v2.z + v3.z);
                acc.w += (v0.w + v1.w) + (v2.w + v3.w);
            }
            for (; j < end; j += 4) {
                int s0 = csr[j];
                float4 v0 = *(const float4*)&hin[(size_t)s0 * F + q * 4];
                acc.x += v0.x; acc.y += v0.y; acc.z += v0.z; acc.w += v0.w;
            }
            acc.x += __shfl_xor(acc.x, 16); acc.y += __shfl_xor(acc.y, 16);
            acc.z += __shfl_xor(acc.z, 16); acc.w += __shfl_xor(acc.w, 16);
            acc.x += __shfl_xor(acc.x, 32); acc.y += __shfl_xor(acc.y, 32);
            acc.z += __shfl_xor(acc.z, 32); acc.w += __shfl_xor(acc.w, 32);
            if (g == 0) {
                float dv = dinv[node];
                float4 bb = *(const float4*)&bvec[q * 4];
                float4 o = make_float4(fmaxf(fmaf(dv, acc.x, bb.x), 0.f),
                                       fmaxf(fmaf(dv, acc.y, bb.y), 0.f),
                                       fmaxf(fmaf(dv, acc.z, bb.z), 0.f),
                                       fmaxf(fmaf(dv, acc.w, bb.w), 0.f));
                Al[r * 16 + (q ^ ((r >> 2) & 7))] = o;
            }
        } else if (g == 0) {
            Al[r * 16 + (q ^ ((r >> 2) & 7))] = make_float4(0.f, 0.f, 0.f, 0.f);
        }
    }
    __syncthreads();

    // ---- gemm phase (K=64) ----
    const int rg = t >> 4, cg = t & 15;
    const int r0 = rg * 4, c0 = cg * 4;
    const int sw = rg & 7;

    float acc[4][4] = {};
#pragma unroll 2
    for (int k4 = 0; k4 < 16; ++k4) {
        float4 a[4];
#pragma unroll
        for (int i = 0; i < 4; ++i) a[i] = Al[(r0 + i) * 16 + (k4 ^ sw)];
#pragma unroll
        for (int j = 0; j < 4; ++j) {
            float4 w = *(const float4*)&Wl[(k4 * 4 + j) * F + c0];
#pragma unroll
            for (int i = 0; i < 4; ++i) {
                float av = (j == 0) ? a[i].x : (j == 1) ? a[i].y : (j == 2) ? a[i].z : a[i].w;
                acc[i][0] = fmaf(av, w.x, acc[i][0]);
                acc[i][1] = fmaf(av, w.y, acc[i][1]);
                acc[i][2] = fmaf(av, w.z, acc[i][2]);
                acc[i][3] = fmaf(av, w.w, acc[i][3]);
            }
        }
    }

#pragma unroll
    for (int i = 0; i < 4; ++i) {
        int gr = row0 + r0 + i;
        if (gr < n) {
            float dv = dinv[gr];
            float4 o = make_float4(acc[i][0] * dv, acc[i][1] * dv,
                                   acc[i][2] * dv, acc[i][3] * dv);
            *(float4*)&hout[(size_t)gr * F + c0] = o;
        }
    }
}

// ============ final aggregation: out = b + dinv * (self + sum), no relu ============
__global__ __launch_bounds__(256) void agg_kernel(
        const int* __restrict__ offsets, const int* __restrict__ csr,
        const float* __restrict__ dinv, const float* __restrict__ h2,
        const float* __restrict__ bvec, float* __restrict__ out, int n) {
    const int wid  = (int)((blockIdx.x * 256u + threadIdx.x) >> 6);
    const int lane = threadIdx.x & 63;
    const int g = lane >> 4, q = lane & 15;
    if (wid >= n) return;

    const int beg = offsets[wid], end = offsets[wid + 1];

    float4 acc = make_float4(0.f, 0.f, 0.f, 0.f);
    if (g == 0) acc = *(const float4*)&h2[(size_t)wid * F + q * 4];   // self term

    int j = beg + g;
    for (; j + 12 < end; j += 16) {               // 4 gathers in flight per lane
        int s0 = csr[j], s1 = csr[j + 4], s2 = csr[j + 8], s3 = csr[j + 12];
        float4 v0 = *(const float4*)&h2[(size_t)s0 * F + q * 4];
        float4 v1 = *(const float4*)&h2[(size_t)s1 * F + q * 4];
        float4 v2 = *(const float4*)&h2[(size_t)s2 * F + q * 4];
        float4 v3 = *(const float4*)&h2[(size_t)s3 * F + q * 4];
        acc.x += (v0.x + v1.x) + (v2.x + v3.x);
        acc.y += (v0.y + v1.y) + (v2.y + v3.y);
        acc.z += (v0.z + v1.z) + (v2.z + v3.z);
        acc.w += (v0.w + v1.w) + (v2.w + v3.w);
    }
    for (; j < end; j += 4) {
        int s0 = csr[j];
        float4 v0 = *(const float4*)&h2[(size_t)s0 * F + q * 4];
        acc.x += v0.x; acc.y += v0.y; acc.z += v0.z; acc.w += v0.w;
    }

    acc.x += __shfl_xor(acc.x, 16); acc.y += __shfl_xor(acc.y, 16);
    acc.z += __shfl_xor(acc.z, 16); acc.w += __shfl_xor(acc.w, 16);
    acc.x += __shfl_xor(acc.x, 32); acc.y += __shfl_xor(acc.y, 32);
    acc.z += __shfl_xor(acc.z, 32); acc.w += __shfl_xor(acc.w, 32);

    if (g == 0) {
        float dv = dinv[wid];
        float4 bb = *(const float4*)&bvec[q * 4];
        float4 o = make_float4(fmaf(dv, acc.x, bb.x), fmaf(dv, acc.y, bb.y),
                               fmaf(dv, acc.z, bb.z), fmaf(dv, acc.w, bb.w));
        *(float4*)&out[(size_t)wid * F + q * 4] = o;
    }
}

// ============ launch ============
extern "C" void kernel_launch(void* const* d_in, const int* in_sizes, int n_in,
                              void* d_out, int out_size, void* d_ws, size_t ws_size,
                              hipStream_t stream) {
    const float* x   = (const float*)d_in[0];
    const float* W1  = (const float*)d_in[1];
    const float* b1  = (const float*)d_in[2];
    const float* W2  = (const float*)d_in[3];
    const float* b2  = (const float*)d_in[4];
    const float* W3  = (const float*)d_in[5];
    const float* b3  = (const float*)d_in[6];
    const int*   ei  = (const int*)d_in[7];

    const int n = in_sizes[0] / D_IN;       // 100000
    const int E = in_sizes[7] / 2;          // 1600000
    const int* src = ei;
    const int* dst = ei + E;

    const int NPB = (n + 255) >> 8;                          // nodes per sub-bucket (391)
    const unsigned long long M37 = ((1ull << 37) / (unsigned long long)NPB) + 1;
    const int cap1 = E / 16 + 4096;                          // L1 bucket capacity (+13 sigma)
    const int cap2 = 8192;                                   // sub-bucket capacity (+24 sigma)

    // ---- workspace layout ----
    char* p = (char*)d_ws;
    auto alloc = [&](size_t bytes) { char* q = p; p += (bytes + 255) & ~(size_t)255; return q; };
    // bcur1[0:16] and bcur2[0:256] in ONE contiguous alloc so one memset covers both
    int*   bcur1   = (int*)  alloc((16 + 256) * 4);
    int*   bcur2   = bcur1 + 16;
    int*   bbase   = (int*)  alloc(256 * 4);
    int*   offsets = (int*)  alloc((size_t)(n + 1) * 4);
    float* dinv    = (float*)alloc((size_t)n * 4);
    int*   csr     = (int*)  alloc((size_t)E * 4);
    float* hA      = (float*)alloc((size_t)n * F * 4);       // 25.6 MB (ping)
    float* hB      = (float*)alloc((size_t)n * F * 4);       // 25.6 MB (pong)
    float* outF    = (float*)d_out;

    // edge buffers alias the (not-yet-live) hA/hB regions:
    // ebufB dies after part2 (gemm1 then writes hA); ebufA dies after bsort
    // (fusedA then writes hB).
    uint2* ebufB = (uint2*)hA;    // 16  * cap1 * 8B = 13.3 MB <= 25.6 MB
    uint2* ebufA = (uint2*)hB;    // 256 * cap2 * 8B = 16.8 MB <= 25.6 MB

    const int p1Blocks = (E + R_EDGES - 1) / R_EDGES;        // 391
    const int gBlocks  = (n + 63) / 64;                      // 1563
    const int aBlocks  = (int)(((size_t)n * 64 + 255) / 256);

    // ---- CSR build (also produces dinv) ----
    hipMemsetAsync(bcur1, 0, (16 + 256) * 4, stream);
    part1_kernel <<<p1Blocks,  256, 0, stream>>>(src, dst, E, M37, cap1, ebufB, bcur1);
    part2_kernel <<<16 * BPB2, 256, 0, stream>>>(ebufB, bcur1, M37, cap1, cap2, ebufA, bcur2);
    scan256_kernel<<<1,        256, 0, stream>>>(bcur2, bbase, offsets, n, E);
    bsort_kernel <<<256,       256, 0, stream>>>(ebufA, bcur2, bbase, cap2, NPB, n,
                                                 csr, offsets, dinv);

    // ---- layer 1 transform: hA = dinv*(x @ W1) ----
    gemm_kernel<D_IN, false><<<gBlocks, 256, 0, stream>>>(x, W1, dinv, hA, n);
    // ---- fused layer1-agg + layer2-transform: hB = dinv*(relu(b1 + dinv*agg(hA)) @ W2) ----
    aggmm_kernel<<<gBlocks, 256, 0, stream>>>(offsets, csr, dinv, hA, b1, W2, hB, n);
    // ---- fused layer2-agg + layer3-transform: hA = dinv*(relu(b2 + dinv*agg(hB)) @ W3) ----
    aggmm_kernel<<<gBlocks, 256, 0, stream>>>(offsets, csr, dinv, hB, b2, W3, hA, n);
    // ---- final aggregation: out = b3 + dinv*agg(hA) ----
    agg_kernel<<<aBlocks, 256, 0, stream>>>(offsets, csr, dinv, hA, b3, outF, n);
}

// Round 9
// 311.630 us; speedup vs baseline: 1.2009x; 1.2009x over previous
//
#include <hip/hip_runtime.h>
#include <hip/hip_bf16.h>

#define D_IN 128
#define F 64          // H1 == H2 == D_OUT == 64
#define R_EDGES 4096  // edges per partition block

// ===================== radix-16 partition, pass 1 (dst high 4 bits of sub-bucket) ==========
__global__ __launch_bounds__(256) void part1_kernel(
        const int* __restrict__ src, const int* __restrict__ dst, int E,
        unsigned long long M37, int cap1, uint2* __restrict__ ebufB,
        int* __restrict__ bcur1) {
    __shared__ int wcnt[64], incl64[64], cur[64], gbase[16];
    const int t = threadIdx.x, w = t >> 6, lane = t & 63;
    const int base = blockIdx.x * R_EDGES;
    const int lim = min(base + R_EDGES, E);

    if (t < 64) wcnt[t] = 0;
    __syncthreads();

    for (int i = base + t; i < lim; i += 256) {
        int d = dst[i];
        int b = (int)(((unsigned long long)(unsigned)d * M37) >> 37) >> 4;
        atomicAdd(&wcnt[b * 4 + w], 1);
    }
    __syncthreads();

    if (t < 64) {                       // exclusive scan, bin-major index b*4+w
        int v = wcnt[t], x = v;
        for (int dlt = 1; dlt < 64; dlt <<= 1) { int y = __shfl_up(x, dlt); if (lane >= dlt) x += y; }
        incl64[t] = x;
        wcnt[t] = x - v;
    }
    __syncthreads();
    if (t < 16) {
        int T = incl64[t * 4 + 3] - (t ? incl64[t * 4 - 1] : 0);
        gbase[t] = T > 0 ? atomicAdd(&bcur1[t], T) : 0;
    }
    __syncthreads();
    if (t < 64) cur[t] = gbase[t >> 2] + wcnt[t] - wcnt[(t >> 2) << 2];
    __syncthreads();

    for (int i = base + t; i < lim; i += 256) {
        int s = src[i], d = dst[i];
        int b = (int)(((unsigned long long)(unsigned)d * M37) >> 37) >> 4;
        int p = atomicAdd(&cur[b * 4 + w], 1);
        ebufB[(size_t)b * cap1 + p] = make_uint2((unsigned)s, (unsigned)d);
    }
}

// ===================== radix-16 partition, pass 2 (low 4 bits) ==========
#define BPB2 27   // blocks per L1 bucket
__global__ __launch_bounds__(256) void part2_kernel(
        const uint2* __restrict__ ebufB, const int* __restrict__ bcur1,
        unsigned long long M37, int cap1, int cap2,
        uint2* __restrict__ ebufA, int* __restrict__ bcur2) {
    __shared__ int wcnt[64], incl64[64], cur[64], gbase[16];
    const int t = threadIdx.x, w = t >> 6, lane = t & 63;
    const int b1 = blockIdx.x / BPB2, r = blockIdx.x % BPB2;
    const int cnt1 = bcur1[b1];
    const int beg = r * R_EDGES, lim = min(beg + R_EDGES, cnt1);
    if (beg >= cnt1) return;
    const uint2* in = ebufB + (size_t)b1 * cap1;

    if (t < 64) wcnt[t] = 0;
    __syncthreads();

    for (int i = beg + t; i < lim; i += 256) {
        unsigned d = in[i].y;
        int b = (int)(((unsigned long long)d * M37) >> 37) & 15;
        atomicAdd(&wcnt[b * 4 + w], 1);
    }
    __syncthreads();

    if (t < 64) {
        int v = wcnt[t], x = v;
        for (int dlt = 1; dlt < 64; dlt <<= 1) { int y = __shfl_up(x, dlt); if (lane >= dlt) x += y; }
        incl64[t] = x;
        wcnt[t] = x - v;
    }
    __syncthreads();
    if (t < 16) {
        int T = incl64[t * 4 + 3] - (t ? incl64[t * 4 - 1] : 0);
        gbase[t] = T > 0 ? atomicAdd(&bcur2[b1 * 16 + t], T) : 0;
    }
    __syncthreads();
    if (t < 64) cur[t] = gbase[t >> 2] + wcnt[t] - wcnt[(t >> 2) << 2];
    __syncthreads();

    for (int i = beg + t; i < lim; i += 256) {
        uint2 e = in[i];
        int b = (int)(((unsigned long long)e.y * M37) >> 37) & 15;
        int p = atomicAdd(&cur[b * 4 + w], 1);
        ebufA[(size_t)(b1 * 16 + b) * cap2 + p] = e;
    }
}

// ===================== sub-bucket csr base scan + offsets[n] ==========
__global__ __launch_bounds__(256) void scan256_kernel(const int* __restrict__ bcur2,
                                                      int* __restrict__ bbase,
                                                      int* __restrict__ offsets, int n, int E) {
    __shared__ int tmp[256];
    int t = threadIdx.x;
    int v = bcur2[t];
    tmp[t] = v;
    __syncthreads();
    for (int off = 1; off < 256; off <<= 1) {
        int a = (t >= off) ? tmp[t - off] : 0;
        __syncthreads();
        if (t >= off) tmp[t] += a;
        __syncthreads();
    }
    bbase[t] = tmp[t] - v;
    if (t == 0) offsets[n] = E;
}

// ===================== per-sub-bucket sort: counts, scan, csr, offsets, dinv ==========
__global__ __launch_bounds__(256) void bsort_kernel(
        const uint2* __restrict__ ebufA, const int* __restrict__ bcur2,
        const int* __restrict__ bbase, int cap2, int NPB, int n,
        int* __restrict__ csr, int* __restrict__ offsets, float* __restrict__ dinv) {
    __shared__ int cnt[512], excl[512];
    const int sb = blockIdx.x, t = threadIdx.x;
    const int node0 = sb * NPB;
    const int nn = min(NPB, n - node0);
    if (nn <= 0) return;
    const int cE = bcur2[sb];
    const int base = bbase[sb];
    const uint2* eb = ebufA + (size_t)sb * cap2;

    for (int i = t; i < 512; i += 256) cnt[i] = 0;
    __syncthreads();
    for (int i = t; i < cE; i += 256) atomicAdd(&cnt[eb[i].y - node0], 1);
    __syncthreads();

    if (t < 64) {                         // scan 512 = 8 chunks of 64, wave 0
        int carry = 0;
        for (int c = 0; c < 8; ++c) {
            int v = cnt[c * 64 + t], x = v;
            for (int dlt = 1; dlt < 64; dlt <<= 1) { int y = __shfl_up(x, dlt); if (t >= dlt) x += y; }
            excl[c * 64 + t] = carry + x - v;
            carry += __shfl(x, 63);
        }
    }
    __syncthreads();

    for (int i = t; i < nn; i += 256) {
        offsets[node0 + i] = base + excl[i];
        dinv[node0 + i] = rsqrtf((float)cnt[i] + 1.0f);
    }
    __syncthreads();
    for (int i = t; i < 512; i += 256) cnt[i] = excl[i];   // cursors
    __syncthreads();
    for (int i = t; i < cE; i += 256) {
        uint2 e = eb[i];
        int p = atomicAdd(&cnt[e.y - node0], 1);
        csr[base + p] = (int)e.x;
    }
}

// ============ GEMM: h2[row] = dinv[row] * (relu?(A[row]) @ W), W is K x 64 ============
// k4 loop unroll CAPPED at 2: full unroll spilled to scratch (R2: 1.7GB traffic).
template<int K, bool RELU_IN>
__global__ __launch_bounds__(256) void gemm_kernel(
        const float* __restrict__ A, const float* __restrict__ W,
        const float* __restrict__ dinv, float* __restrict__ h2, int n) {
    constexpr int F4 = K / 4;
    __shared__ float4 Al[64 * F4];            // swizzled: phys k4 = k4 ^ ((r>>2) & 7)
    __shared__ float  Wl[K * F];
    const int t = threadIdx.x;

    for (int i = t; i < K * F / 4; i += 256)
        ((float4*)Wl)[i] = ((const float4*)W)[i];

    const int row0 = blockIdx.x * 64;
    for (int i = t; i < 64 * F4; i += 256) {
        int r = i / F4, k4 = i % F4;
        int gr = row0 + r; if (gr >= n) gr = n - 1;
        float4 v = ((const float4*)(A + (size_t)gr * K))[k4];
        if (RELU_IN) {
            v.x = fmaxf(v.x, 0.f); v.y = fmaxf(v.y, 0.f);
            v.z = fmaxf(v.z, 0.f); v.w = fmaxf(v.w, 0.f);
        }
        Al[r * F4 + (k4 ^ ((r >> 2) & 7))] = v;
    }
    __syncthreads();

    const int rg = t >> 4, cg = t & 15;
    const int r0 = rg * 4, c0 = cg * 4;
    const int sw = rg & 7;

    float acc[4][4] = {};
#pragma unroll 2
    for (int k4 = 0; k4 < F4; ++k4) {
        float4 a[4];
#pragma unroll
        for (int i = 0; i < 4; ++i) a[i] = Al[(r0 + i) * F4 + (k4 ^ sw)];
#pragma unroll
        for (int j = 0; j < 4; ++j) {
            float4 w = *(const float4*)&Wl[(k4 * 4 + j) * F + c0];
#pragma unroll
            for (int i = 0; i < 4; ++i) {
                float av = (j == 0) ? a[i].x : (j == 1) ? a[i].y : (j == 2) ? a[i].z : a[i].w;
                acc[i][0] = fmaf(av, w.x, acc[i][0]);
                acc[i][1] = fmaf(av, w.y, acc[i][1]);
                acc[i][2] = fmaf(av, w.z, acc[i][2]);
                acc[i][3] = fmaf(av, w.w, acc[i][3]);
            }
        }
    }

#pragma unroll
    for (int i = 0; i < 4; ++i) {
        int gr = row0 + r0 + i;
        if (gr < n) {
            float dv = dinv[gr];
            float4 o = make_float4(acc[i][0] * dv, acc[i][1] * dv,
                                   acc[i][2] * dv, acc[i][3] * dv);
            *(float4*)&h2[(size_t)gr * F + c0] = o;
        }
    }
}

// ============ aggregation: out[i] = b + dinv[i] * (h2[i] + sum_{s in in(i)} h2[s]) ============
// One wave per node. Lane = (edge-slot g in 0..7, feature-octet q8 in 0..7): each lane
// loads 2x float4 (32B) of its slot's row, 8 slots x 2-deep unroll = 16 row-gathers
// in flight per wave with distinct accumulator legs (forces VGPRs to hold loads).
// Reduce across slots via shfl_xor(8,16,32); lanes g==0 store the 256B output row.
__global__ __launch_bounds__(256) void agg_kernel(
        const int* __restrict__ offsets, const int* __restrict__ csr,
        const float* __restrict__ dinv, const float* __restrict__ h2,
        const float* __restrict__ bvec, float* __restrict__ out, int n) {
    const int wid  = (int)((blockIdx.x * 256u + threadIdx.x) >> 6);
    const int lane = threadIdx.x & 63;
    const int g = lane >> 3, q8 = lane & 7;
    if (wid >= n) return;
    const size_t fo = (size_t)q8 * 8;          // this lane's 32B chunk within the row

    const int beg = offsets[wid], end = offsets[wid + 1];

    float4 a00 = {0,0,0,0}, a01 = {0,0,0,0};   // leg 0 accumulator (8 floats)
    float4 a10 = {0,0,0,0}, a11 = {0,0,0,0};   // leg 1 accumulator
    if (g == 0) {
        a00 = *(const float4*)&h2[(size_t)wid * F + fo];
        a01 = *(const float4*)&h2[(size_t)wid * F + fo + 4];
    }

    int j = beg + g;
    for (; j + 8 < end; j += 16) {             // 16 rows in flight across the wave
        int s0 = csr[j], s1 = csr[j + 8];
        const float* r0 = &h2[(size_t)s0 * F + fo];
        const float* r1 = &h2[(size_t)s1 * F + fo];
        float4 v00 = *(const float4*)r0;
        float4 v01 = *(const float4*)(r0 + 4);
        float4 v10 = *(const float4*)r1;
        float4 v11 = *(const float4*)(r1 + 4);
        a00.x += v00.x; a00.y += v00.y; a00.z += v00.z; a00.w += v00.w;
        a01.x += v01.x; a01.y += v01.y; a01.z += v01.z; a01.w += v01.w;
        a10.x += v10.x; a10.y += v10.y; a10.z += v10.z; a10.w += v10.w;
        a11.x += v11.x; a11.y += v11.y; a11.z += v11.z; a11.w += v11.w;
    }
    if (j < end) {
        int s0 = csr[j];
        const float* r0 = &h2[(size_t)s0 * F + fo];
        float4 v00 = *(const float4*)r0;
        float4 v01 = *(const float4*)(r0 + 4);
        a00.x += v00.x; a00.y += v00.y; a00.z += v00.z; a00.w += v00.w;
        a01.x += v01.x; a01.y += v01.y; a01.z += v01.z; a01.w += v01.w;
    }
    a00.x += a10.x; a00.y += a10.y; a00.z += a10.z; a00.w += a10.w;
    a01.x += a11.x; a01.y += a11.y; a01.z += a11.z; a01.w += a11.w;

    // reduce across the 8 edge-slots
#pragma unroll
    for (int m = 8; m < 64; m <<= 1) {
        a00.x += __shfl_xor(a00.x, m); a00.y += __shfl_xor(a00.y, m);
        a00.z += __shfl_xor(a00.z, m); a00.w += __shfl_xor(a00.w, m);
        a01.x += __shfl_xor(a01.x, m); a01.y += __shfl_xor(a01.y, m);
        a01.z += __shfl_xor(a01.z, m); a01.w += __shfl_xor(a01.w, m);
    }

    if (g == 0) {
        float dv = dinv[wid];
        float4 b0 = *(const float4*)&bvec[fo];
        float4 b1 = *(const float4*)&bvec[fo + 4];
        float4 o0 = make_float4(fmaf(dv, a00.x, b0.x), fmaf(dv, a00.y, b0.y),
                                fmaf(dv, a00.z, b0.z), fmaf(dv, a00.w, b0.w));
        float4 o1 = make_float4(fmaf(dv, a01.x, b1.x), fmaf(dv, a01.y, b1.y),
                                fmaf(dv, a01.z, b1.z), fmaf(dv, a01.w, b1.w));
        *(float4*)&out[(size_t)wid * F + fo] = o0;
        *(float4*)&out[(size_t)wid * F + fo + 4] = o1;
    }
}

// ============ launch ============
extern "C" void kernel_launch(void* const* d_in, const int* in_sizes, int n_in,
                              void* d_out, int out_size, void* d_ws, size_t ws_size,
                              hipStream_t stream) {
    const float* x   = (const float*)d_in[0];
    const float* W1  = (const float*)d_in[1];
    const float* b1  = (const float*)d_in[2];
    const float* W2  = (const float*)d_in[3];
    const float* b2  = (const float*)d_in[4];
    const float* W3  = (const float*)d_in[5];
    const float* b3  = (const float*)d_in[6];
    const int*   ei  = (const int*)d_in[7];

    const int n = in_sizes[0] / D_IN;       // 100000
    const int E = in_sizes[7] / 2;          // 1600000
    const int* src = ei;
    const int* dst = ei + E;

    const int NPB = (n + 255) >> 8;                          // nodes per sub-bucket (391)
    const unsigned long long M37 = ((1ull << 37) / (unsigned long long)NPB) + 1;
    const int cap1 = E / 16 + 4096;                          // L1 bucket capacity (+13 sigma)
    const int cap2 = 8192;                                   // sub-bucket capacity (+24 sigma)

    // ---- workspace layout ----
    char* p = (char*)d_ws;
    auto alloc = [&](size_t bytes) { char* q = p; p += (bytes + 255) & ~(size_t)255; return q; };
    // bcur1[0:16] and bcur2[0:256] in ONE contiguous alloc so one memset covers both
    int*   bcur1   = (int*)  alloc((16 + 256) * 4);
    int*   bcur2   = bcur1 + 16;
    int*   bbase   = (int*)  alloc(256 * 4);
    int*   offsets = (int*)  alloc((size_t)(n + 1) * 4);
    float* dinv    = (float*)alloc((size_t)n * 4);
    int*   csr     = (int*)  alloc((size_t)E * 4);
    float* h2      = (float*)alloc((size_t)n * F * 4);       // 25.6 MB
    float* outA    = (float*)alloc((size_t)n * F * 4);       // 25.6 MB
    float* outF    = (float*)d_out;

    // edge buffers alias the (not-yet-live) h2/outA regions
    uint2* ebufB = (uint2*)h2;    // 16  * cap1 * 8B = 13.3 MB <= 25.6 MB
    uint2* ebufA = (uint2*)outA;  // 256 * cap2 * 8B = 16.8 MB <= 25.6 MB

    const int p1Blocks = (E + R_EDGES - 1) / R_EDGES;        // 391
    const int gBlocks  = (n + 63) / 64;
    const int aBlocks  = (int)(((size_t)n * 64 + 255) / 256);

    // ---- CSR build (also produces dinv) ----
    hipMemsetAsync(bcur1, 0, (16 + 256) * 4, stream);
    part1_kernel <<<p1Blocks,  256, 0, stream>>>(src, dst, E, M37, cap1, ebufB, bcur1);
    part2_kernel <<<16 * BPB2, 256, 0, stream>>>(ebufB, bcur1, M37, cap1, cap2, ebufA, bcur2);
    scan256_kernel<<<1,        256, 0, stream>>>(bcur2, bbase, offsets, n, E);
    bsort_kernel <<<256,       256, 0, stream>>>(ebufA, bcur2, bbase, cap2, NPB, n,
                                                 csr, offsets, dinv);

    // ---- layer 1: x (K=128) ----
    gemm_kernel<D_IN, false><<<gBlocks, 256, 0, stream>>>(x, W1, dinv, h2, n);
    agg_kernel<<<aBlocks, 256, 0, stream>>>(offsets, csr, dinv, h2, b1, outA, n);

    // ---- layer 2: relu(outA) (K=64) ----
    gemm_kernel<F, true><<<gBlocks, 256, 0, stream>>>(outA, W2, dinv, h2, n);
    agg_kernel<<<aBlocks, 256, 0, stream>>>(offsets, csr, dinv, h2, b2, outA, n);

    // ---- layer 3: relu(outA) (K=64) ----
    gemm_kernel<F, true><<<gBlocks, 256, 0, stream>>>(outA, W3, dinv, h2, n);
    agg_kernel<<<aBlocks, 256, 0, stream>>>(offsets, csr, dinv, h2, b3, outF, n);
}

// Round 10
// 302.184 us; speedup vs baseline: 1.2385x; 1.0313x over previous
//
#include <hip/hip_runtime.h>
#include <hip/hip_bf16.h>

#define D_IN 128
#define F 64          // H1 == H2 == D_OUT == 64
#define R_EDGES 4096  // edges per partition block

// ===================== ONE-PASS 256-bin partition ==========
// Per 4096-edge block: LDS count over 256 dst-range bins, ONE global atomic per
// nonempty bin to reserve space in the final sub-bucket layout, then direct
// scatter of packed (src,dst). Per-block per-bin segments avg 16 edges = 128B
// (full L2 lines). Replaces the old part1+part2 two-pass radix build.
__global__ __launch_bounds__(256) void part256_kernel(
        const int* __restrict__ src, const int* __restrict__ dst, int E,
        unsigned long long M37, int cap2,
        uint2* __restrict__ ebufA, int* __restrict__ bcur2) {
    __shared__ int cnt[256], gb[256];
    const int t = threadIdx.x;
    const int base = blockIdx.x * R_EDGES;
    const int lim = min(base + R_EDGES, E);

    cnt[t] = 0;
    __syncthreads();

    for (int i = base + t; i < lim; i += 256) {
        int b = (int)(((unsigned long long)(unsigned)dst[i] * M37) >> 37);
        atomicAdd(&cnt[b], 1);
    }
    __syncthreads();

    int c = cnt[t];
    gb[t] = (c > 0) ? atomicAdd(&bcur2[t], c) : 0;
    cnt[t] = 0;                    // reuse as block-local cursor
    __syncthreads();

    for (int i = base + t; i < lim; i += 256) {
        int s = src[i], d = dst[i];
        int b = (int)(((unsigned long long)(unsigned)d * M37) >> 37);
        int p = atomicAdd(&cnt[b], 1);
        ebufA[(size_t)b * cap2 + gb[b] + p] = make_uint2((unsigned)s, (unsigned)d);
    }
}

// ===================== per-sub-bucket sort: counts, scan, csr, offsets, dinv ==========
// One block per sub-bucket (~391 nodes, ~6250 edges). All per-edge atomics are LDS.
// Each block computes its own csr base by scanning bcur2[256] in-block (no scan kernel).
__global__ __launch_bounds__(256) void bsort_kernel(
        const uint2* __restrict__ ebufA, const int* __restrict__ bcur2,
        int cap2, int NPB, int n, int E,
        int* __restrict__ csr, int* __restrict__ offsets, float* __restrict__ dinv) {
    __shared__ int cnt[512], excl[512], bb[256];
    const int sb = blockIdx.x, t = threadIdx.x;
    const int node0 = sb * NPB;
    const int nn = min(NPB, n - node0);

    // inline exclusive scan of bcur2[256] (4 chunks of 64, wave 0)
    bb[t] = bcur2[t];
    __syncthreads();
    if (t < 64) {
        int carry = 0;
        for (int c4 = 0; c4 < 4; ++c4) {
            int v = bb[c4 * 64 + t], x = v;
            for (int dlt = 1; dlt < 64; dlt <<= 1) { int y = __shfl_up(x, dlt); if (t >= dlt) x += y; }
            bb[c4 * 64 + t] = carry + x - v;     // exclusive
            carry += __shfl(x, 63);
        }
    }
    __syncthreads();

    if (sb == 255 && t == 0) offsets[n] = E;
    if (nn <= 0) return;
    const int cE = bcur2[sb];
    const int base = bb[sb];
    const uint2* eb = ebufA + (size_t)sb * cap2;

    for (int i = t; i < 512; i += 256) cnt[i] = 0;
    __syncthreads();
    for (int i = t; i < cE; i += 256) atomicAdd(&cnt[eb[i].y - node0], 1);
    __syncthreads();

    if (t < 64) {                         // scan 512 = 8 chunks of 64, wave 0
        int carry = 0;
        for (int c4 = 0; c4 < 8; ++c4) {
            int v = cnt[c4 * 64 + t], x = v;
            for (int dlt = 1; dlt < 64; dlt <<= 1) { int y = __shfl_up(x, dlt); if (t >= dlt) x += y; }
            excl[c4 * 64 + t] = carry + x - v;
            carry += __shfl(x, 63);
        }
    }
    __syncthreads();

    for (int i = t; i < nn; i += 256) {
        offsets[node0 + i] = base + excl[i];
        dinv[node0 + i] = rsqrtf((float)cnt[i] + 1.0f);
    }
    __syncthreads();
    for (int i = t; i < 512; i += 256) cnt[i] = excl[i];   // cursors
    __syncthreads();
    for (int i = t; i < cE; i += 256) {
        uint2 e = eb[i];
        int p = atomicAdd(&cnt[e.y - node0], 1);
        csr[base + p] = (int)e.x;
    }
}

// ============ GEMM: h2[row] = dinv[row] * (relu?(A[row]) @ W), W is K x 64 ============
// k4 loop unroll CAPPED at 2: full unroll spilled to scratch (R2: 1.7GB traffic).
template<int K, bool RELU_IN>
__global__ __launch_bounds__(256) void gemm_kernel(
        const float* __restrict__ A, const float* __restrict__ W,
        const float* __restrict__ dinv, float* __restrict__ h2, int n) {
    constexpr int F4 = K / 4;
    __shared__ float4 Al[64 * F4];            // swizzled: phys k4 = k4 ^ ((r>>2) & 7)
    __shared__ float  Wl[K * F];
    const int t = threadIdx.x;

    for (int i = t; i < K * F / 4; i += 256)
        ((float4*)Wl)[i] = ((const float4*)W)[i];

    const int row0 = blockIdx.x * 64;
    for (int i = t; i < 64 * F4; i += 256) {
        int r = i / F4, k4 = i % F4;
        int gr = row0 + r; if (gr >= n) gr = n - 1;
        float4 v = ((const float4*)(A + (size_t)gr * K))[k4];
        if (RELU_IN) {
            v.x = fmaxf(v.x, 0.f); v.y = fmaxf(v.y, 0.f);
            v.z = fmaxf(v.z, 0.f); v.w = fmaxf(v.w, 0.f);
        }
        Al[r * F4 + (k4 ^ ((r >> 2) & 7))] = v;
    }
    __syncthreads();

    const int rg = t >> 4, cg = t & 15;
    const int r0 = rg * 4, c0 = cg * 4;
    const int sw = rg & 7;

    float acc[4][4] = {};
#pragma unroll 2
    for (int k4 = 0; k4 < F4; ++k4) {
        float4 a[4];
#pragma unroll
        for (int i = 0; i < 4; ++i) a[i] = Al[(r0 + i) * F4 + (k4 ^ sw)];
#pragma unroll
        for (int j = 0; j < 4; ++j) {
            float4 w = *(const float4*)&Wl[(k4 * 4 + j) * F + c0];
#pragma unroll
            for (int i = 0; i < 4; ++i) {
                float av = (j == 0) ? a[i].x : (j == 1) ? a[i].y : (j == 2) ? a[i].z : a[i].w;
                acc[i][0] = fmaf(av, w.x, acc[i][0]);
                acc[i][1] = fmaf(av, w.y, acc[i][1]);
                acc[i][2] = fmaf(av, w.z, acc[i][2]);
                acc[i][3] = fmaf(av, w.w, acc[i][3]);
            }
        }
    }

#pragma unroll
    for (int i = 0; i < 4; ++i) {
        int gr = row0 + r0 + i;
        if (gr < n) {
            float dv = dinv[gr];
            float4 o = make_float4(acc[i][0] * dv, acc[i][1] * dv,
                                   acc[i][2] * dv, acc[i][3] * dv);
            *(float4*)&h2[(size_t)gr * F + c0] = o;
        }
    }
}

// ============ aggregation: out[i] = b + dinv[i] * (h2[i] + sum_{s in in(i)} h2[s]) ============
// One wave per node. Lane = (edge-slot g in 0..7, feature-octet q8 in 0..7): each lane
// loads 2x float4 (32B) of its slot's row, 8 slots x 2-deep unroll = 16 row-gathers
// in flight per wave. Reduce across slots via shfl_xor(8,16,32).
// NOTE: flat at ~62us across two MLP shapes (R7/R9) with FETCH at the 8-XCD
// compulsory floor (~190MB) -> at the random-gather fabric ceiling; do not touch.
__global__ __launch_bounds__(256) void agg_kernel(
        const int* __restrict__ offsets, const int* __restrict__ csr,
        const float* __restrict__ dinv, const float* __restrict__ h2,
        const float* __restrict__ bvec, float* __restrict__ out, int n) {
    const int wid  = (int)((blockIdx.x * 256u + threadIdx.x) >> 6);
    const int lane = threadIdx.x & 63;
    const int g = lane >> 3, q8 = lane & 7;
    if (wid >= n) return;
    const size_t fo = (size_t)q8 * 8;          // this lane's 32B chunk within the row

    const int beg = offsets[wid], end = offsets[wid + 1];

    float4 a00 = {0,0,0,0}, a01 = {0,0,0,0};   // leg 0 accumulator (8 floats)
    float4 a10 = {0,0,0,0}, a11 = {0,0,0,0};   // leg 1 accumulator
    if (g == 0) {
        a00 = *(const float4*)&h2[(size_t)wid * F + fo];
        a01 = *(const float4*)&h2[(size_t)wid * F + fo + 4];
    }

    int j = beg + g;
    for (; j + 8 < end; j += 16) {             // 16 rows in flight across the wave
        int s0 = csr[j], s1 = csr[j + 8];
        const float* r0 = &h2[(size_t)s0 * F + fo];
        const float* r1 = &h2[(size_t)s1 * F + fo];
        float4 v00 = *(const float4*)r0;
        float4 v01 = *(const float4*)(r0 + 4);
        float4 v10 = *(const float4*)r1;
        float4 v11 = *(const float4*)(r1 + 4);
        a00.x += v00.x; a00.y += v00.y; a00.z += v00.z; a00.w += v00.w;
        a01.x += v01.x; a01.y += v01.y; a01.z += v01.z; a01.w += v01.w;
        a10.x += v10.x; a10.y += v10.y; a10.z += v10.z; a10.w += v10.w;
        a11.x += v11.x; a11.y += v11.y; a11.z += v11.z; a11.w += v11.w;
    }
    if (j < end) {
        int s0 = csr[j];
        const float* r0 = &h2[(size_t)s0 * F + fo];
        float4 v00 = *(const float4*)r0;
        float4 v01 = *(const float4*)(r0 + 4);
        a00.x += v00.x; a00.y += v00.y; a00.z += v00.z; a00.w += v00.w;
        a01.x += v01.x; a01.y += v01.y; a01.z += v01.z; a01.w += v01.w;
    }
    a00.x += a10.x; a00.y += a10.y; a00.z += a10.z; a00.w += a10.w;
    a01.x += a11.x; a01.y += a11.y; a01.z += a11.z; a01.w += a11.w;

    // reduce across the 8 edge-slots
#pragma unroll
    for (int m = 8; m < 64; m <<= 1) {
        a00.x += __shfl_xor(a00.x, m); a00.y += __shfl_xor(a00.y, m);
        a00.z += __shfl_xor(a00.z, m); a00.w += __shfl_xor(a00.w, m);
        a01.x += __shfl_xor(a01.x, m); a01.y += __shfl_xor(a01.y, m);
        a01.z += __shfl_xor(a01.z, m); a01.w += __shfl_xor(a01.w, m);
    }

    if (g == 0) {
        float dv = dinv[wid];
        float4 b0 = *(const float4*)&bvec[fo];
        float4 b1 = *(const float4*)&bvec[fo + 4];
        float4 o0 = make_float4(fmaf(dv, a00.x, b0.x), fmaf(dv, a00.y, b0.y),
                                fmaf(dv, a00.z, b0.z), fmaf(dv, a00.w, b0.w));
        float4 o1 = make_float4(fmaf(dv, a01.x, b1.x), fmaf(dv, a01.y, b1.y),
                                fmaf(dv, a01.z, b1.z), fmaf(dv, a01.w, b1.w));
        *(float4*)&out[(size_t)wid * F + fo] = o0;
        *(float4*)&out[(size_t)wid * F + fo + 4] = o1;
    }
}

// ============ launch ============
extern "C" void kernel_launch(void* const* d_in, const int* in_sizes, int n_in,
                              void* d_out, int out_size, void* d_ws, size_t ws_size,
                              hipStream_t stream) {
    const float* x   = (const float*)d_in[0];
    const float* W1  = (const float*)d_in[1];
    const float* b1  = (const float*)d_in[2];
    const float* W2  = (const float*)d_in[3];
    const float* b2  = (const float*)d_in[4];
    const float* W3  = (const float*)d_in[5];
    const float* b3  = (const float*)d_in[6];
    const int*   ei  = (const int*)d_in[7];

    const int n = in_sizes[0] / D_IN;       // 100000
    const int E = in_sizes[7] / 2;          // 1600000
    const int* src = ei;
    const int* dst = ei + E;

    const int NPB = (n + 255) >> 8;                          // nodes per sub-bucket (391)
    const unsigned long long M37 = ((1ull << 37) / (unsigned long long)NPB) + 1;
    const int cap2 = 8192;                                   // sub-bucket capacity (+24 sigma)

    // ---- workspace layout ----
    char* p = (char*)d_ws;
    auto alloc = [&](size_t bytes) { char* q = p; p += (bytes + 255) & ~(size_t)255; return q; };
    int*   bcur2   = (int*)  alloc(256 * 4);
    int*   offsets = (int*)  alloc((size_t)(n + 1) * 4);
    float* dinv    = (float*)alloc((size_t)n * 4);
    int*   csr     = (int*)  alloc((size_t)E * 4);
    float* h2      = (float*)alloc((size_t)n * F * 4);       // 25.6 MB
    float* outA    = (float*)alloc((size_t)n * F * 4);       // 25.6 MB
    float* outF    = (float*)d_out;

    // edge buffer aliases the (not-yet-live) outA region: ebufA dies after bsort,
    // outA first written by agg1.
    uint2* ebufA = (uint2*)outA;  // 256 * cap2 * 8B = 16.8 MB <= 25.6 MB

    const int pBlocks = (E + R_EDGES - 1) / R_EDGES;         // 391
    const int gBlocks = (n + 63) / 64;
    const int aBlocks = (int)(((size_t)n * 64 + 255) / 256);

    // ---- CSR build (also produces dinv) ----
    hipMemsetAsync(bcur2, 0, 256 * 4, stream);
    part256_kernel<<<pBlocks, 256, 0, stream>>>(src, dst, E, M37, cap2, ebufA, bcur2);
    bsort_kernel  <<<256,     256, 0, stream>>>(ebufA, bcur2, cap2, NPB, n, E,
                                                csr, offsets, dinv);

    // ---- layer 1: x (K=128) ----
    gemm_kernel<D_IN, false><<<gBlocks, 256, 0, stream>>>(x, W1, dinv, h2, n);
    agg_kernel<<<aBlocks, 256, 0, stream>>>(offsets, csr, dinv, h2, b1, outA, n);

    // ---- layer 2: relu(outA) (K=64) ----
    gemm_kernel<F, true><<<gBlocks, 256, 0, stream>>>(outA, W2, dinv, h2, n);
    agg_kernel<<<aBlocks, 256, 0, stream>>>(offsets, csr, dinv, h2, b2, outA, n);

    // ---- layer 3: relu(outA) (K=64) ----
    gemm_kernel<F, true><<<gBlocks, 256, 0, stream>>>(outA, W3, dinv, h2, n);
    agg_kernel<<<aBlocks, 256, 0, stream>>>(offsets, csr, dinv, h2, b3, outF, n);
}